// Round 1
// baseline (1891.606 us; speedup 1.0000x reference)
//
#include <hip/hip_runtime.h>

// ---------------------------------------------------------------------------
// SimVP Decoder, fp32 baseline.
// Pipeline (GN+SiLU of each ConvSC deferred into the consumer's input load):
//   conv0(hid raw) + PixelShuffle -> A[16,64,80,80]        (pre-norm)
//   reduce A -> st0
//   conv1(GN_SiLU(A)) -> Bb[16,64,80,80]                   (pre-norm)
//   reduce Bb -> st1
//   conv2(GN_SiLU(Bb)) + PixelShuffle -> Cb[16,64,160,160] (pre-norm)
//   reduce Cb -> st2
//   conv3(GN_SiLU(Cb) + enc1) -> Db[16,64,160,160]         (pre-norm)
//   reduce Db -> st3
//   readout: Y = 1x1conv(GN_SiLU(Db))  [16,3,160,160]
//   feamap:  argx = conv(Y, fw, stride 4)/16, first 3 ch   [16,3,40,40]
//   nz:      nzinv[b,c,l] = 1/(count_nonzero(attn row)+1e-5)
//   final:   out = Y * (1 + corr), corr via einsum+fold indexing
// ---------------------------------------------------------------------------

#define DEVFN static __device__ __forceinline__

constexpr int CH  = 64;   // hidden channels
constexpr int CC  = 16;   // input-channel chunk staged in LDS
constexpr int OCB = 32;   // output channels per block

DEVFN float silu_f(float t) { return t / (1.f + __expf(-t)); }

// ---- weight repack: [OC][64][3][3] -> [(ic*9+tap)][OC] so per-(ic,tap) the
//      OCB weights are contiguous & block-uniform -> scalar s_load_dwordx8.
template<int OC>
__global__ void repack_k(const float* __restrict__ src, float* __restrict__ dst) {
  int i = blockIdx.x * 256 + threadIdx.x;
  if (i >= OC * CH * 9) return;
  int oc = i / (CH * 9);
  int r  = i - oc * (CH * 9);     // ic*9 + tap
  dst[r * OC + oc] = src[i];
}

__global__ void zero_k(float* __restrict__ p, int n) {
  int i = blockIdx.x * 256 + threadIdx.x;
  if (i < n) p[i] = 0.f;
}

// ---- per-(b,group) sum & sumsq over contiguous 32*HW floats --------------
template<int HW, int SLICES>
__global__ void reduce_k(const float* __restrict__ buf, float* __restrict__ st) {
  const int bg = blockIdx.x / SLICES;
  const int sl = blockIdx.x % SLICES;
  const float4* p = (const float4*)(buf + (size_t)bg * 32 * HW);
  const int n4 = 32 * HW / 4;
  float s = 0.f, s2 = 0.f;
  for (int i = sl * 256 + threadIdx.x; i < n4; i += SLICES * 256) {
    float4 v = p[i];
    s  += (v.x + v.y) + (v.z + v.w);
    s2 += v.x * v.x + v.y * v.y + v.z * v.z + v.w * v.w;
  }
  #pragma unroll
  for (int o = 32; o > 0; o >>= 1) {
    s  += __shfl_down(s, o);
    s2 += __shfl_down(s2, o);
  }
  __shared__ float ws[4][2];
  int wid = threadIdx.x >> 6, lane = threadIdx.x & 63;
  if (lane == 0) { ws[wid][0] = s; ws[wid][1] = s2; }
  __syncthreads();
  if (threadIdx.x == 0) {
    float a = 0.f, b = 0.f;
    #pragma unroll
    for (int i = 0; i < 4; ++i) { a += ws[i][0]; b += ws[i][1]; }
    atomicAdd(&st[bg * 2 + 0], a);
    atomicAdd(&st[bg * 2 + 1], b);
  }
}

// ---- direct 3x3 conv, pad 1, fused input transform + optional PixelShuffle
// MODE: 0 = raw input; 1 = GN+SiLU(in); 2 = GN+SiLU(in) + addsrc
template<int HIN, int WIN, int TH, int OC, int MODE, bool PSF>
__global__ __launch_bounds__(TH * WIN)
void conv3_k(const float* __restrict__ in, const float* __restrict__ wrp,
             const float* __restrict__ bias, const float* __restrict__ gw,
             const float* __restrict__ gb, const float* __restrict__ st,
             const float* __restrict__ addsrc, float* __restrict__ out)
{
  constexpr int NT = TH * WIN;
  constexpr int LH = TH + 2;
  constexpr int LW = WIN + 2;
  __shared__ float sIn[CC][LH][LW];   // [ic][row][col]: lane-consecutive cols

  const int tid = threadIdx.x;
  const int ty  = tid / WIN;
  const int tx  = tid - ty * WIN;
  const int b   = blockIdx.y / (OC / OCB);
  const int ob  = blockIdx.y % (OC / OCB);
  const int h0  = blockIdx.x * TH;

  float mean0 = 0.f, rstd0 = 0.f, mean1 = 0.f, rstd1 = 0.f;
  if (MODE >= 1) {
    const float N = 32.f * HIN * WIN;
    float s0 = st[(b * 2 + 0) * 2], q0 = st[(b * 2 + 0) * 2 + 1];
    float s1 = st[(b * 2 + 1) * 2], q1 = st[(b * 2 + 1) * 2 + 1];
    mean0 = s0 / N; rstd0 = rsqrtf(q0 / N - mean0 * mean0 + 1e-5f);
    mean1 = s1 / N; rstd1 = rsqrtf(q1 / N - mean1 * mean1 + 1e-5f);
  }

  float acc[OCB];
  #pragma unroll
  for (int i = 0; i < OCB; ++i) acc[i] = bias[ob * OCB + i];

  for (int cc = 0; cc < CH / CC; ++cc) {
    __syncthreads();
    // stage CC channels of the (TH+2)x(WIN+2) halo tile, transformed
    for (int e = tid; e < CC * LH * LW; e += NT) {
      int ic  = e / (LH * LW);
      int rr  = e - ic * (LH * LW);
      int r   = rr / LW;
      int col = rr - r * LW;
      int gh = h0 + r - 1, gx = col - 1;
      float v = 0.f;
      if (gh >= 0 && gh < HIN && (unsigned)gx < (unsigned)WIN) {
        int c = cc * CC + ic;
        size_t off = ((size_t)(b * CH + c) * HIN + gh) * WIN + gx;
        float x = in[off];
        if (MODE >= 1) {
          float m  = (c < 32) ? mean0 : mean1;
          float rs = (c < 32) ? rstd0 : rstd1;
          float t = (x - m) * rs * gw[c] + gb[c];
          x = silu_f(t);
          if (MODE == 2) x += addsrc[off];
        }
        v = x;
      }
      (&sIn[0][0][0])[e] = v;
    }
    __syncthreads();
    // accumulate: 1 LDS read + OCB scalar-weight FMAs per (ic, tap)
    for (int ic = 0; ic < CC; ++ic) {
      const float* wb = wrp + (size_t)((cc * CC + ic) * 9) * OC + ob * OCB;
      #pragma unroll
      for (int dy = 0; dy < 3; ++dy) {
        #pragma unroll
        for (int dx = 0; dx < 3; ++dx) {
          float v = sIn[ic][ty + dy][tx + dx];
          const float* wp = wb + (dy * 3 + dx) * OC;
          #pragma unroll
          for (int i = 0; i < OCB; ++i) acc[i] = fmaf(v, wp[i], acc[i]);
        }
      }
    }
  }

  const int h = h0 + ty, w = tx;
  if (!PSF) {
    #pragma unroll
    for (int i = 0; i < OCB; ++i) {
      int oc = ob * OCB + i;
      out[((size_t)(b * OC + oc) * HIN + h) * WIN + w] = acc[i];
    }
  } else {
    // PixelShuffle(2): convout[b, c*4+r*2+s, h, w] -> out[b, c, 2h+r, 2w+s]
    #pragma unroll
    for (int i = 0; i < OCB; ++i) {
      int oc = ob * OCB + i;
      int c = oc >> 2, rbit = (oc >> 1) & 1, sbit = oc & 1;
      out[((size_t)(b * (OC / 4) + c) * (2 * HIN) + (2 * h + rbit)) * (2 * WIN)
          + (2 * w + sbit)] = acc[i];
    }
  }
}

// ---- readout: Y[b,o,pix] = rb[o] + sum_c GN_SiLU(D)[b,c,pix] * rw[o,c] ----
__global__ void readout_k(const float* __restrict__ D, const float* __restrict__ st,
                          const float* __restrict__ gw, const float* __restrict__ gb,
                          const float* __restrict__ rw, const float* __restrict__ rb,
                          float* __restrict__ Y)
{
  int idx = blockIdx.x * 256 + threadIdx.x;
  if (idx >= 16 * 25600) return;
  int b = idx / 25600, pix = idx - b * 25600;
  const float N = 32.f * 25600.f;
  float mean[2], rstd[2];
  #pragma unroll
  for (int g = 0; g < 2; ++g) {
    float s = st[(b * 2 + g) * 2], q = st[(b * 2 + g) * 2 + 1];
    float m = s / N;
    mean[g] = m; rstd[g] = rsqrtf(q / N - m * m + 1e-5f);
  }
  float a0 = rb[0], a1 = rb[1], a2 = rb[2];
  const float* dp = D + (size_t)(b * 64) * 25600 + pix;
  #pragma unroll 4
  for (int c = 0; c < 64; ++c) {
    float x = dp[(size_t)c * 25600];
    float t = (x - mean[c >> 5]) * rstd[c >> 5] * gw[c] + gb[c];
    float v = silu_f(t);
    a0 = fmaf(v, rw[c], a0);
    a1 = fmaf(v, rw[64 + c], a1);
    a2 = fmaf(v, rw[128 + c], a2);
  }
  Y[(size_t)(b * 3 + 0) * 25600 + pix] = a0;
  Y[(size_t)(b * 3 + 1) * 25600 + pix] = a1;
  Y[(size_t)(b * 3 + 2) * 25600 + pix] = a2;
}

// ---- feamap: argx[b,o,i,j] = (1/16) sum_{c<3,u,v<4} Y[b,c,4i+u,4j+v]*fw[o,c,u,v]
__global__ void feamap_k(const float* __restrict__ Y, const float* __restrict__ fw,
                         float* __restrict__ argx)
{
  int idx = blockIdx.x * 256 + threadIdx.x;
  if (idx >= 16 * 3 * 1600) return;
  int b  = idx / (3 * 1600);
  int o  = (idx / 1600) % 3;
  int ij = idx % 1600;
  int i = ij / 40, j = ij - i * 40;
  float s = 0.f;
  #pragma unroll
  for (int c = 0; c < 3; ++c)
    #pragma unroll
    for (int u = 0; u < 4; ++u)
      #pragma unroll
      for (int v = 0; v < 4; ++v)
        s += Y[((size_t)(b * 3 + c) * 160 + (4 * i + u)) * 160 + (4 * j + v)]
             * fw[((o * 3 + c) * 4 + u) * 4 + v];
  argx[idx] = s * (1.f / 16.f);
}

// ---- nzinv[b,c,l] = 1 / (count_nonzero(attn[b,c,l,:]) + 1e-5) -------------
__global__ void nz_k(const float* __restrict__ attn, float* __restrict__ nzinv) {
  int idx = blockIdx.x * 256 + threadIdx.x;
  if (idx >= 16 * 3 * 256) return;
  const float* p = attn + (size_t)idx * 16;
  int c = 0;
  #pragma unroll
  for (int k = 0; k < 16; ++k) c += (p[k] != 0.f);
  nzinv[idx] = 1.f / ((float)c + 1e-5f);
}

// ---- final: out[b,c,y,x] = Y * (1 + sum_k attn[b,c,l,k]*inv * patch(k)) ---
// l=(y/10)*16+(x/10); patch(k)=argx[b,c,(k>>2)*10+y%10,(k&3)*10+x%10]
__global__ void final_k(const float* __restrict__ Y, const float* __restrict__ attn,
                        const float* __restrict__ nzinv, const float* __restrict__ argx,
                        float* __restrict__ out)
{
  int idx = blockIdx.x * 256 + threadIdx.x;
  if (idx >= 16 * 3 * 25600) return;
  int bc  = idx / 25600;
  int pix = idx - bc * 25600;
  int y = pix / 160, x = pix - y * 160;
  int l  = (y / 10) * 16 + (x / 10);
  int pi = y % 10,  pj = x % 10;
  const float* ar = attn + ((size_t)bc * 256 + l) * 16;
  const float* ax = argx + (size_t)bc * 1600;
  float inv = nzinv[bc * 256 + l];
  float corr = 0.f;
  #pragma unroll
  for (int k = 0; k < 16; ++k)
    corr += ar[k] * ax[((k >> 2) * 10 + pi) * 40 + ((k & 3) * 10 + pj)];
  float yv = Y[idx];
  out[idx] = yv * (1.f + corr * inv);
}

// ---------------------------------------------------------------------------
extern "C" void kernel_launch(void* const* d_in, const int* in_sizes, int n_in,
                              void* d_out, int out_size, void* d_ws, size_t ws_size,
                              hipStream_t stream)
{
  const float* attn = (const float*)d_in[0];
  const float* hid  = (const float*)d_in[1];
  const float* enc1 = (const float*)d_in[2];
  const float* d0w  = (const float*)d_in[3];
  const float* d0b  = (const float*)d_in[4];
  const float* d0gw = (const float*)d_in[5];
  const float* d0gb = (const float*)d_in[6];
  const float* d1w  = (const float*)d_in[7];
  const float* d1b  = (const float*)d_in[8];
  const float* d1gw = (const float*)d_in[9];
  const float* d1gb = (const float*)d_in[10];
  const float* d2w  = (const float*)d_in[11];
  const float* d2b  = (const float*)d_in[12];
  const float* d2gw = (const float*)d_in[13];
  const float* d2gb = (const float*)d_in[14];
  const float* d3w  = (const float*)d_in[15];
  const float* d3b  = (const float*)d_in[16];
  const float* d3gw = (const float*)d_in[17];
  const float* d3gb = (const float*)d_in[18];
  const float* rw   = (const float*)d_in[19];
  const float* rb   = (const float*)d_in[20];
  const float* fw   = (const float*)d_in[21];

  float* ws = (float*)d_ws;
  size_t o = 0;
  float* A    = ws + o; o += (size_t)16 * 64 * 80 * 80;    // 6,553,600
  float* Bb   = ws + o; o += (size_t)16 * 64 * 80 * 80;
  float* Cb   = ws + o; o += (size_t)16 * 64 * 160 * 160;  // 26,214,400
  float* Db   = ws + o; o += (size_t)16 * 64 * 160 * 160;
  float* Y    = ws + o; o += (size_t)16 * 3 * 160 * 160;
  float* argx = ws + o; o += (size_t)16 * 3 * 40 * 40;
  float* nzv  = ws + o; o += (size_t)16 * 3 * 256;
  float* st   = ws + o; o += 256;                          // 4 stages x 32 x 2
  float* w0   = ws + o; o += (size_t)64 * 9 * 256;
  float* w1   = ws + o; o += (size_t)64 * 9 * 64;
  float* w2   = ws + o; o += (size_t)64 * 9 * 256;
  float* w3   = ws + o; o += (size_t)64 * 9 * 64;

  // stats must be zeroed every call (atomics accumulate)
  zero_k<<<1, 256, 0, stream>>>(st, 256);

  repack_k<256><<<(256 * 576 + 255) / 256, 256, 0, stream>>>(d0w, w0);
  repack_k<64><<<(64 * 576 + 255) / 256, 256, 0, stream>>>(d1w, w1);
  repack_k<256><<<(256 * 576 + 255) / 256, 256, 0, stream>>>(d2w, w2);
  repack_k<64><<<(64 * 576 + 255) / 256, 256, 0, stream>>>(d3w, w3);

  // stage 0: conv(hid) + PS -> A (pre-norm)
  conv3_k<40, 40, 8, 256, 0, true>
    <<<dim3(5, 16 * (256 / OCB)), 320, 0, stream>>>(hid, w0, d0b,
      nullptr, nullptr, nullptr, nullptr, A);
  reduce_k<6400, 16><<<32 * 16, 256, 0, stream>>>(A, st + 0);

  // stage 1: conv(GN_SiLU(A)) -> Bb
  conv3_k<80, 80, 4, 64, 1, false>
    <<<dim3(20, 16 * (64 / OCB)), 320, 0, stream>>>(A, w1, d1b,
      d0gw, d0gb, st + 0, nullptr, Bb);
  reduce_k<6400, 16><<<32 * 16, 256, 0, stream>>>(Bb, st + 64);

  // stage 2: conv(GN_SiLU(Bb)) + PS -> Cb
  conv3_k<80, 80, 4, 256, 1, true>
    <<<dim3(20, 16 * (256 / OCB)), 320, 0, stream>>>(Bb, w2, d2b,
      d1gw, d1gb, st + 64, nullptr, Cb);
  reduce_k<25600, 64><<<32 * 64, 256, 0, stream>>>(Cb, st + 128);

  // stage 3: conv(GN_SiLU(Cb) + enc1) -> Db
  conv3_k<160, 160, 2, 64, 2, false>
    <<<dim3(80, 16 * (64 / OCB)), 320, 0, stream>>>(Cb, w3, d3b,
      d2gw, d2gb, st + 128, enc1, Db);
  reduce_k<25600, 64><<<32 * 64, 256, 0, stream>>>(Db, st + 192);

  // readout: Y = 1x1conv(GN_SiLU(Db))
  readout_k<<<(16 * 25600 + 255) / 256, 256, 0, stream>>>(Db, st + 192,
      d3gw, d3gb, rw, rb, Y);

  // feamap conv (stride 4) / 16, first 3 output channels only
  feamap_k<<<(16 * 3 * 1600 + 255) / 256, 256, 0, stream>>>(Y, fw, argx);

  // nz counts
  nz_k<<<(16 * 3 * 256 + 255) / 256, 256, 0, stream>>>(attn, nzv);

  // fused einsum + fold + (1+corr)*Y
  final_k<<<(16 * 3 * 25600 + 255) / 256, 256, 0, stream>>>(Y, attn, nzv, argx,
      (float*)d_out);
}

// Round 2
// 1393.196 us; speedup vs baseline: 1.3577x; 1.3577x over previous
//
#include <hip/hip_runtime.h>

// ---------------------------------------------------------------------------
// SimVP Decoder, fp32, round 2.
//   pad(hid) -> hidP
//   conv0(hidP) + PS -> A (pre-norm)            [stats fused into epilogue]
//   act1: GN_SiLU(A) -> Ap (padded)
//   conv1(Ap) -> Bb (pre-norm)                  [stats fused]
//   act2: GN_SiLU(Bb) -> Bp (padded)
//   conv2(Bp) + PS -> Cb (pre-norm)             [stats fused]
//   act3: GN_SiLU(Cb) + enc1 -> Cp (padded)
//   conv3(Cp) -> Db (pre-norm)                  [stats fused]
//   readout: Y = 1x1conv(GN_SiLU(Db))
//   feamap -> argx ; nz ; final: out = Y*(1+corr)
// All conv inputs are zero-padded -> staging loop is branchless.
// ---------------------------------------------------------------------------

#define DEVFN static __device__ __forceinline__

constexpr int CHN = 64;   // hidden channels
constexpr int OCB = 32;   // output channels per block

DEVFN float silu_f(float t) { return t / (1.f + __expf(-t)); }

// ---- weight repack: [OC][64][3][3] -> [(ic*9+tap)][OC] (block-uniform rows)
template<int OC>
__global__ void repack_k(const float* __restrict__ src, float* __restrict__ dst) {
  int i = blockIdx.x * 256 + threadIdx.x;
  if (i >= OC * CHN * 9) return;
  int oc = i / (CHN * 9);
  int r  = i - oc * (CHN * 9);
  dst[r * OC + oc] = src[i];
}

__global__ void zero_k(float* __restrict__ p, int n) {
  int i = blockIdx.x * 256 + threadIdx.x;
  if (i < n) p[i] = 0.f;
}

// ---- activation pass into padded buffer -----------------------------------
// MODE: 0 = plain copy (pad only); 1 = GN+SiLU; 2 = GN+SiLU + add
template<int HIN, int WIN, int MODE>
__global__ void act_k(const float* __restrict__ in, const float* __restrict__ st,
                      const float* __restrict__ gw, const float* __restrict__ gb,
                      const float* __restrict__ addsrc, float* __restrict__ outP)
{
  constexpr int HP = HIN + 2, WP = WIN + 2;
  int idx = blockIdx.x * 256 + threadIdx.x;
  if (idx >= 16 * CHN * HP * WP) return;
  int x = idx % WP;
  int y = (idx / WP) % HP;
  int c = (idx / (WP * HP)) % CHN;
  int b = idx / (WP * HP * CHN);
  float v = 0.f;
  if (x >= 1 && x <= WIN && y >= 1 && y <= HIN) {
    size_t off = ((size_t)(b * CHN + c) * HIN + (y - 1)) * WIN + (x - 1);
    v = in[off];
    if (MODE >= 1) {
      const float N = 32.f * HIN * WIN;
      int g = c >> 5;
      float s = st[(b * 2 + g) * 2], q = st[(b * 2 + g) * 2 + 1];
      float m = s / N;
      float rs = rsqrtf(q / N - m * m + 1e-5f);
      v = silu_f((v - m) * rs * gw[c] + gb[c]);
      if (MODE == 2) v += addsrc[off];
    }
  }
  outP[idx] = v;
}

// ---- direct 3x3 conv from padded input, stats fused, optional PixelShuffle
template<int HIN, int WIN, int TH, int CC, int OC, bool PSF>
__global__ __launch_bounds__(TH * WIN)
void conv3_k(const float* __restrict__ inP, const float* __restrict__ wrp,
             const float* __restrict__ bias, float* __restrict__ out,
             float* __restrict__ stp)
{
  constexpr int NT = TH * WIN;
  constexpr int LH = TH + 2;
  constexpr int LW = WIN + 2;
  constexpr int HP = HIN + 2, WP = WIN + 2;
  __shared__ float sIn[CC][LH][LW];
  __shared__ float red[16][2];

  const int tid = threadIdx.x;
  const int ty  = tid / WIN;
  const int tx  = tid - ty * WIN;
  const int b   = blockIdx.y / (OC / OCB);
  const int ob  = blockIdx.y % (OC / OCB);
  const int h0  = blockIdx.x * TH;

  float acc[OCB];
  #pragma unroll
  for (int i = 0; i < OCB; ++i) acc[i] = bias[ob * OCB + i];

  for (int cc = 0; cc < CHN / CC; ++cc) {
    __syncthreads();
    // branchless staging from padded buffer
    const float* src = inP + ((size_t)(b * CHN + cc * CC) * HP + h0) * WP;
    for (int e = tid; e < CC * LH * LW; e += NT) {
      int ic  = e / (LH * LW);
      int rr  = e - ic * (LH * LW);
      int r   = rr / LW;
      int col = rr - r * LW;
      (&sIn[0][0][0])[e] = src[(size_t)ic * HP * WP + (size_t)r * WP + col];
    }
    __syncthreads();
    for (int ic = 0; ic < CC; ++ic) {
      const float* wb = wrp + (size_t)((cc * CC + ic) * 9) * OC + ob * OCB;
      #pragma unroll
      for (int dy = 0; dy < 3; ++dy) {
        #pragma unroll
        for (int dx = 0; dx < 3; ++dx) {
          float v = sIn[ic][ty + dy][tx + dx];
          const float* wp = wb + (dy * 3 + dx) * OC;
          #pragma unroll
          for (int i = 0; i < OCB; ++i) acc[i] = fmaf(v, wp[i], acc[i]);
        }
      }
    }
  }

  const int h = h0 + ty, w = tx;
  if (!PSF) {
    #pragma unroll
    for (int i = 0; i < OCB; ++i) {
      int oc = ob * OCB + i;
      out[((size_t)(b * OC + oc) * HIN + h) * WIN + w] = acc[i];
    }
  } else {
    #pragma unroll
    for (int i = 0; i < OCB; ++i) {
      int oc = ob * OCB + i;
      int c = oc >> 2, rbit = (oc >> 1) & 1, sbit = oc & 1;
      out[((size_t)(b * (OC / 4) + c) * (2 * HIN) + (2 * h + rbit)) * (2 * WIN)
          + (2 * w + sbit)] = acc[i];
    }
  }

  // fused GroupNorm statistics: all OCB channels of this block are one group
  float s = 0.f, s2 = 0.f;
  #pragma unroll
  for (int i = 0; i < OCB; ++i) { s += acc[i]; s2 += acc[i] * acc[i]; }
  #pragma unroll
  for (int o = 32; o > 0; o >>= 1) {
    s  += __shfl_down(s, o);
    s2 += __shfl_down(s2, o);
  }
  int wid = tid >> 6;
  if ((tid & 63) == 0) { red[wid][0] = s; red[wid][1] = s2; }
  __syncthreads();
  if (tid == 0) {
    float a = 0.f, q = 0.f;
    #pragma unroll
    for (int i = 0; i < NT / 64; ++i) { a += red[i][0]; q += red[i][1]; }
    int grp = PSF ? (ob >> 2) : ob;
    atomicAdd(&stp[(b * 2 + grp) * 2 + 0], a);
    atomicAdd(&stp[(b * 2 + grp) * 2 + 1], q);
  }
}

// ---- readout: Y[b,o,pix] = rb[o] + sum_c GN_SiLU(D)[b,c,pix] * rw[o,c] ----
__global__ void readout_k(const float* __restrict__ D, const float* __restrict__ st,
                          const float* __restrict__ gw, const float* __restrict__ gb,
                          const float* __restrict__ rw, const float* __restrict__ rb,
                          float* __restrict__ Y)
{
  int idx = blockIdx.x * 256 + threadIdx.x;
  if (idx >= 16 * 25600) return;
  int b = idx / 25600, pix = idx - b * 25600;
  const float N = 32.f * 25600.f;
  float mean[2], rstd[2];
  #pragma unroll
  for (int g = 0; g < 2; ++g) {
    float s = st[(b * 2 + g) * 2], q = st[(b * 2 + g) * 2 + 1];
    float m = s / N;
    mean[g] = m; rstd[g] = rsqrtf(q / N - m * m + 1e-5f);
  }
  float a0 = rb[0], a1 = rb[1], a2 = rb[2];
  const float* dp = D + (size_t)(b * 64) * 25600 + pix;
  #pragma unroll 4
  for (int c = 0; c < 64; ++c) {
    float x = dp[(size_t)c * 25600];
    float t = (x - mean[c >> 5]) * rstd[c >> 5] * gw[c] + gb[c];
    float v = silu_f(t);
    a0 = fmaf(v, rw[c], a0);
    a1 = fmaf(v, rw[64 + c], a1);
    a2 = fmaf(v, rw[128 + c], a2);
  }
  Y[(size_t)(b * 3 + 0) * 25600 + pix] = a0;
  Y[(size_t)(b * 3 + 1) * 25600 + pix] = a1;
  Y[(size_t)(b * 3 + 2) * 25600 + pix] = a2;
}

// ---- feamap: argx = conv(Y, fw, stride 4)/16, first 3 channels ------------
__global__ void feamap_k(const float* __restrict__ Y, const float* __restrict__ fw,
                         float* __restrict__ argx)
{
  int idx = blockIdx.x * 256 + threadIdx.x;
  if (idx >= 16 * 3 * 1600) return;
  int b  = idx / (3 * 1600);
  int o  = (idx / 1600) % 3;
  int ij = idx % 1600;
  int i = ij / 40, j = ij - i * 40;
  float s = 0.f;
  #pragma unroll
  for (int c = 0; c < 3; ++c)
    #pragma unroll
    for (int u = 0; u < 4; ++u)
      #pragma unroll
      for (int v = 0; v < 4; ++v)
        s += Y[((size_t)(b * 3 + c) * 160 + (4 * i + u)) * 160 + (4 * j + v)]
             * fw[((o * 3 + c) * 4 + u) * 4 + v];
  argx[idx] = s * (1.f / 16.f);
}

__global__ void nz_k(const float* __restrict__ attn, float* __restrict__ nzinv) {
  int idx = blockIdx.x * 256 + threadIdx.x;
  if (idx >= 16 * 3 * 256) return;
  const float* p = attn + (size_t)idx * 16;
  int c = 0;
  #pragma unroll
  for (int k = 0; k < 16; ++k) c += (p[k] != 0.f);
  nzinv[idx] = 1.f / ((float)c + 1e-5f);
}

__global__ void final_k(const float* __restrict__ Y, const float* __restrict__ attn,
                        const float* __restrict__ nzinv, const float* __restrict__ argx,
                        float* __restrict__ out)
{
  int idx = blockIdx.x * 256 + threadIdx.x;
  if (idx >= 16 * 3 * 25600) return;
  int bc  = idx / 25600;
  int pix = idx - bc * 25600;
  int y = pix / 160, x = pix - y * 160;
  int l  = (y / 10) * 16 + (x / 10);
  int pi = y % 10,  pj = x % 10;
  const float* ar = attn + ((size_t)bc * 256 + l) * 16;
  const float* ax = argx + (size_t)bc * 1600;
  float inv = nzinv[bc * 256 + l];
  float corr = 0.f;
  #pragma unroll
  for (int k = 0; k < 16; ++k)
    corr += ar[k] * ax[((k >> 2) * 10 + pi) * 40 + ((k & 3) * 10 + pj)];
  float yv = Y[idx];
  out[idx] = yv * (1.f + corr * inv);
}

// ---------------------------------------------------------------------------
extern "C" void kernel_launch(void* const* d_in, const int* in_sizes, int n_in,
                              void* d_out, int out_size, void* d_ws, size_t ws_size,
                              hipStream_t stream)
{
  const float* attn = (const float*)d_in[0];
  const float* hid  = (const float*)d_in[1];
  const float* enc1 = (const float*)d_in[2];
  const float* d0w  = (const float*)d_in[3];
  const float* d0b  = (const float*)d_in[4];
  const float* d0gw = (const float*)d_in[5];
  const float* d0gb = (const float*)d_in[6];
  const float* d1w  = (const float*)d_in[7];
  const float* d1b  = (const float*)d_in[8];
  const float* d1gw = (const float*)d_in[9];
  const float* d1gb = (const float*)d_in[10];
  const float* d2w  = (const float*)d_in[11];
  const float* d2b  = (const float*)d_in[12];
  const float* d2gw = (const float*)d_in[13];
  const float* d2gb = (const float*)d_in[14];
  const float* d3w  = (const float*)d_in[15];
  const float* d3b  = (const float*)d_in[16];
  const float* d3gw = (const float*)d_in[17];
  const float* d3gb = (const float*)d_in[18];
  const float* rw   = (const float*)d_in[19];
  const float* rb   = (const float*)d_in[20];
  const float* fw   = (const float*)d_in[21];

  float* ws = (float*)d_ws;
  size_t o = 0;
  // buf1: A / Bb, later Y+argx+nzv
  float* buf1 = ws + o; o += (size_t)16 * 64 * 80 * 80;          // 6,553,600
  // buf2: Ap / Bp (padded 82x82)
  float* buf2 = ws + o; o += (size_t)16 * 64 * 82 * 82;          // 6,885,376
  // Cb / Db
  float* bufC = ws + o; o += (size_t)16 * 64 * 160 * 160;        // 26,214,400
  // Cp (padded 162x162); head also reused as hidP (padded 42x42) early on
  float* bufCp = ws + o; o += (size_t)16 * 64 * 162 * 162;       // 26,873,856
  float* st   = ws + o; o += 256;
  float* w0   = ws + o; o += (size_t)64 * 9 * 256;
  float* w1   = ws + o; o += (size_t)64 * 9 * 64;
  float* w2   = ws + o; o += (size_t)64 * 9 * 256;
  float* w3   = ws + o; o += (size_t)64 * 9 * 64;

  float* A    = buf1;
  float* Bb   = buf1;
  float* Ap   = buf2;
  float* Bp   = buf2;
  float* Cb   = bufC;
  float* Db   = bufC;
  float* Cp   = bufCp;
  float* hidP = bufCp;                       // dead before Cp is written
  float* Y    = buf1;                        // Bb dead after act2
  float* argx = buf1 + (size_t)16 * 3 * 25600;
  float* nzv  = argx + (size_t)16 * 3 * 1600;

  zero_k<<<1, 256, 0, stream>>>(st, 256);

  repack_k<256><<<(256 * 576 + 255) / 256, 256, 0, stream>>>(d0w, w0);
  repack_k<64><<<(64 * 576 + 255) / 256, 256, 0, stream>>>(d1w, w1);
  repack_k<256><<<(256 * 576 + 255) / 256, 256, 0, stream>>>(d2w, w2);
  repack_k<64><<<(64 * 576 + 255) / 256, 256, 0, stream>>>(d3w, w3);

  // pad hid -> hidP [16,64,42,42]
  act_k<40, 40, 0><<<(16 * 64 * 42 * 42 + 255) / 256, 256, 0, stream>>>(
      hid, nullptr, nullptr, nullptr, nullptr, hidP);

  // stage 0: conv(hidP) + PS -> A (pre-norm), stats -> st+0
  conv3_k<40, 40, 8, 16, 256, true>
    <<<dim3(5, 16 * 8), 320, 0, stream>>>(hidP, w0, d0b, A, st + 0);

  // act1: GN_SiLU(A) -> Ap [16,64,82,82]
  act_k<80, 80, 1><<<(16 * 64 * 82 * 82 + 255) / 256, 256, 0, stream>>>(
      A, st + 0, d0gw, d0gb, nullptr, Ap);

  // stage 1: conv(Ap) -> Bb (pre-norm), stats -> st+64
  conv3_k<80, 80, 4, 16, 64, false>
    <<<dim3(20, 16 * 2), 320, 0, stream>>>(Ap, w1, d1b, Bb, st + 64);

  // act2: GN_SiLU(Bb) -> Bp
  act_k<80, 80, 1><<<(16 * 64 * 82 * 82 + 255) / 256, 256, 0, stream>>>(
      Bb, st + 64, d1gw, d1gb, nullptr, Bp);

  // stage 2: conv(Bp) + PS -> Cb (pre-norm), stats -> st+128
  conv3_k<80, 80, 4, 16, 256, true>
    <<<dim3(20, 16 * 8), 320, 0, stream>>>(Bp, w2, d2b, Cb, st + 128);

  // act3: GN_SiLU(Cb) + enc1 -> Cp [16,64,162,162]
  act_k<160, 160, 2><<<(16 * 64 * 162 * 162 + 255) / 256, 256, 0, stream>>>(
      Cb, st + 128, d2gw, d2gb, enc1, Cp);

  // stage 3: conv(Cp) -> Db (pre-norm), stats -> st+192
  conv3_k<160, 160, 4, 8, 64, false>
    <<<dim3(40, 16 * 2), 640, 0, stream>>>(Cp, w3, d3b, Db, st + 192);

  // readout: Y = 1x1conv(GN_SiLU(Db))
  readout_k<<<(16 * 25600 + 255) / 256, 256, 0, stream>>>(Db, st + 192,
      d3gw, d3gb, rw, rb, Y);

  feamap_k<<<(16 * 3 * 1600 + 255) / 256, 256, 0, stream>>>(Y, fw, argx);
  nz_k<<<(16 * 3 * 256 + 255) / 256, 256, 0, stream>>>(attn, nzv);
  final_k<<<(16 * 3 * 25600 + 255) / 256, 256, 0, stream>>>(Y, attn, nzv, argx,
      (float*)d_out);
}

// Round 4
// 707.928 us; speedup vs baseline: 2.6720x; 1.9680x over previous
//
#include <hip/hip_runtime.h>

// ---------------------------------------------------------------------------
// SimVP Decoder, round 4: bf16 MFMA implicit-GEMM convs (parity-fixed swizzle).
//   pad(hid) -> hidP (NHWC bf16 padded)
//   conv0(hidP)+PS -> A (NCHW f32, stats fused)
//   act1: GN_SiLU(A) -> Ap (NHWC bf16 padded)
//   conv1(Ap) -> Bb ; act2 -> Bp ; conv2(Bp)+PS -> Cb
//   act3: GN_SiLU(Cb)+enc1 -> Cp ; conv3(Cp) -> Db
//   readout -> Y ; feamap -> argx ; nz ; final
// Conv = implicit GEMM: C[oc][px] = sum_k W[oc][k] X[k][px], k = tap*64+ic.
// LDS input tile rows are padded to LWS (multiple of 8) pixels so the XOR
// chunk swizzle parity (pix & 7) == (col & 7) holds on read and write.
// ---------------------------------------------------------------------------

#define DEVFN static __device__ __forceinline__

typedef short v8s __attribute__((ext_vector_type(8)));
typedef float v4f __attribute__((ext_vector_type(4)));

DEVFN float silu_f(float t) { return t / (1.f + __expf(-t)); }

DEVFN ushort f2bf(float x) {
  union { float f; unsigned u; } t; t.f = x;
  unsigned r = t.u + 0x7FFFu + ((t.u >> 16) & 1u);
  return (ushort)(r >> 16);
}

__global__ void zero_k(float* __restrict__ p, int n) {
  int i = blockIdx.x * 256 + threadIdx.x;
  if (i < n) p[i] = 0.f;
}

// ---- weight repack: [OC][64][3][3] f32 -> bf16 [kc=tap*8+ic/8][OC][8] -----
template<int OC>
__global__ void repackw_k(const float* __restrict__ src, ushort* __restrict__ dst) {
  int i = blockIdx.x * 256 + threadIdx.x;
  if (i >= OC * 576) return;
  int oc = i / 576, r = i - oc * 576;      // r = ic*9 + tap
  int ic = r / 9, tap = r - ic * 9;
  int kc = tap * 8 + (ic >> 3), j = ic & 7;
  dst[((size_t)kc * OC + oc) * 8 + j] = f2bf(src[i]);
}

// ---- zero the 1-px border of a padded NHWC bf16 buffer --------------------
template<int HP, int WP>
__global__ void border_k(ushort* __restrict__ outP) {
  int idx = blockIdx.x * 256 + threadIdx.x;
  if (idx >= 16 * HP * WP) return;
  int p = idx % (HP * WP);
  int y = p / WP, x = p - y * WP;
  if (y == 0 || y == HP - 1 || x == 0 || x == WP - 1) {
    uint4 z = {0u, 0u, 0u, 0u};
    uint4* dst = (uint4*)(outP + (size_t)idx * 64);
    #pragma unroll
    for (int k = 0; k < 8; ++k) dst[k] = z;
  }
}

// ---- act: NCHW f32 -> padded NHWC bf16 via swizzled LDS transpose ---------
// MODE: 0 copy; 1 GN+SiLU; 2 GN+SiLU + addsrc
template<int HW_TOT, int WOUT, int MODE>
__global__ __launch_bounds__(256)
void act_k(const float* __restrict__ in, const float* __restrict__ st,
           const float* __restrict__ gw, const float* __restrict__ gb,
           const float* __restrict__ addsrc, ushort* __restrict__ outP)
{
  constexpr int HOUT = HW_TOT / WOUT;
  constexpr int WP = WOUT + 2, HP = HOUT + 2;
  __shared__ uint4 sT[256 * 8];            // [pixel][slot], slot = cc ^ (pix&7)
  const int tid = threadIdx.x;
  constexpr int NBLK = (HW_TOT + 255) / 256;
  const int b  = blockIdx.x / NBLK;
  const int p0 = (blockIdx.x - b * NBLK) * 256;
  const int px = p0 + tid;

  float mean[2], rstd[2];
  if (MODE >= 1) {
    const float N = 32.f * HW_TOT;
    #pragma unroll
    for (int g = 0; g < 2; ++g) {
      float s = st[(b * 2 + g) * 2], q = st[(b * 2 + g) * 2 + 1];
      float m = s / N;
      mean[g] = m; rstd[g] = rsqrtf(q / N - m * m + 1e-5f);
    }
  }
  if (px < HW_TOT) {
    const float* ip = in + (size_t)b * 64 * HW_TOT + px;
    #pragma unroll 2
    for (int cc = 0; cc < 8; ++cc) {
      unsigned w[4];
      #pragma unroll
      for (int jp = 0; jp < 4; ++jp) {
        float v0, v1;
        #pragma unroll
        for (int h = 0; h < 2; ++h) {
          int c = cc * 8 + jp * 2 + h;
          float v = ip[(size_t)c * HW_TOT];
          if (MODE >= 1) {
            v = silu_f((v - mean[c >> 5]) * rstd[c >> 5] * gw[c] + gb[c]);
            if (MODE == 2) v += addsrc[(size_t)(b * 64 + c) * HW_TOT + px];
          }
          if (h == 0) v0 = v; else v1 = v;
        }
        w[jp] = (unsigned)f2bf(v0) | ((unsigned)f2bf(v1) << 16);
      }
      uint4 pk = {w[0], w[1], w[2], w[3]};
      sT[tid * 8 + (cc ^ (tid & 7))] = pk;
    }
  }
  __syncthreads();
  const int o = tid & 7, pr = tid >> 3;
  #pragma unroll
  for (int i = 0; i < 8; ++i) {
    int p = i * 32 + pr;
    int gpx = p0 + p;
    if (gpx < HW_TOT) {
      int y = gpx / WOUT, x = gpx - y * WOUT;
      uint4 val = sT[p * 8 + (o ^ (p & 7))];
      *(uint4*)(outP + (((size_t)(b * HP) + y + 1) * WP + (x + 1)) * 64 + o * 8) = val;
    }
  }
}

// ---- MFMA implicit-GEMM 3x3 conv ------------------------------------------
// inP: padded NHWC bf16; wrep: [72][OCT][8] bf16; out: NCHW f32 (post-PS if PSF)
template<int HIN, int WIN, int TH, int WT, int NG, int OCT, bool PSF>
__global__ __launch_bounds__(256)
void convm_k(const uint4* __restrict__ inP, const ushort* __restrict__ wrep,
             const float* __restrict__ bias, float* __restrict__ out,
             float* __restrict__ stp)
{
  constexpr int HP = HIN + 2, WP = WIN + 2;
  constexpr int LH = TH + 2, LW = WT + 2;
  constexpr int NOCB = OCT / 64;
  // LDS row stride (pixels): multiple of 8 so (pix&7)==(col&7); must cover
  // the widest read col (NG*16-1 + 2 for ragged tiles).
  constexpr int LRD = (NG * 16 + 2 > LW) ? (NG * 16 + 2) : LW;
  constexpr int LWS = (LRD + 7) & ~7;
  constexpr int NCHUNK = LH * LWS * 8;                // 16B chunks in tile
  __shared__ uint4 sQ[NCHUNK];

  const int tid  = threadIdx.x;
  const int lane = tid & 63;
  const int wave = tid >> 6;
  const int sub  = lane >> 4;        // 0..3
  const int lx   = lane & 15;
  const int b    = blockIdx.y / NOCB;
  const int ocb  = blockIdx.y - b * NOCB;
  constexpr int NTX = WIN / WT;
  const int tx   = blockIdx.x % NTX;
  const int tyy  = blockIdx.x / NTX;
  const int x0   = tx * WT;
  const int y0   = tyy * TH;
  const int oc0  = ocb * 64 + wave * 16;

  // stage input tile, swizzled: sQ[p*8+slot] = chunk (slot ^ (col&7)) of
  // pixel p = r*LWS + col; cols >= LW zero-filled.
  const uint4* gsrc = inP + ((size_t)(b * HP + y0) * WP + x0) * 8;
  for (int q = tid; q < NCHUNK; q += 256) {
    int p = q >> 3, slot = q & 7;
    int r = p / LWS, cx = p - r * LWS;
    int icc = slot ^ (cx & 7);
    uint4 v = {0u, 0u, 0u, 0u};
    if (cx < LW) v = gsrc[((size_t)r * WP + cx) * 8 + icc];
    sQ[q] = v;
  }

  // A-fragments: weights for this wave's 16 oc, all 18 k-chunks, in regs
  v8s afrag[18];
  #pragma unroll
  for (int t = 0; t < 18; ++t) {
    int kc = t * 4 + sub;
    afrag[t] = ((const v8s*)wrep)[(size_t)kc * OCT + oc0 + lx];
  }
  float bvals[4];
  #pragma unroll
  for (int j = 0; j < 4; ++j) bvals[j] = bias[oc0 + sub * 4 + j];

  __syncthreads();

  float spart = 0.f, qpart = 0.f;

  for (int gy = 0; gy < TH; ++gy) {
    #pragma unroll
    for (int xg = 0; xg < NG; ++xg) {
      v4f acc = {bvals[0], bvals[1], bvals[2], bvals[3]};
      #pragma unroll
      for (int t = 0; t < 18; ++t) {
        const int tap = t >> 1, half = t & 1;
        const int dy = tap / 3, dx = tap - dy * 3;
        int col = xg * 16 + lx + dx;
        int idx = ((gy + dy) * LWS + col) * 8 + ((half * 4 + sub) ^ (col & 7));
        v8s bf = __builtin_bit_cast(v8s, sQ[idx]);
        acc = __builtin_amdgcn_mfma_f32_16x16x32_bf16(afrag[t], bf, acc, 0, 0, 0);
      }
      const int x = x0 + xg * 16 + lx;
      const int y = y0 + gy;
      const bool valid = (NG * 16 == WT) || (x < WIN);
      if (valid) {
        if (!PSF) {
          #pragma unroll
          for (int j = 0; j < 4; ++j) {
            int oc = oc0 + sub * 4 + j;
            out[((size_t)(b * OCT + oc) * HIN + y) * WIN + x] = acc[j];
          }
        } else {
          #pragma unroll
          for (int j = 0; j < 4; ++j) {
            int oc = oc0 + sub * 4 + j;
            int c = oc >> 2, rr = (oc >> 1) & 1, ss = oc & 1;
            out[((size_t)(b * 64 + c) * (2 * HIN) + (2 * y + rr)) * (2 * WIN)
                + (2 * x + ss)] = acc[j];
          }
        }
        #pragma unroll
        for (int j = 0; j < 4; ++j) { spart += acc[j]; qpart += acc[j] * acc[j]; }
      }
    }
  }

  // fused GroupNorm stats (all 16 oc of this wave are in one group)
  #pragma unroll
  for (int o = 32; o >= 1; o >>= 1) {
    spart += __shfl_down(spart, o);
    qpart += __shfl_down(qpart, o);
  }
  if (lane == 0) {
    int grp = PSF ? (oc0 >> 7) : (oc0 >> 5);
    atomicAdd(&stp[(b * 2 + grp) * 2 + 0], spart);
    atomicAdd(&stp[(b * 2 + grp) * 2 + 1], qpart);
  }
}

// ---- readout: Y[b,o,pix] = rb[o] + sum_c GN_SiLU(D)[b,c,pix] * rw[o,c] ----
__global__ void readout_k(const float* __restrict__ D, const float* __restrict__ st,
                          const float* __restrict__ gw, const float* __restrict__ gb,
                          const float* __restrict__ rw, const float* __restrict__ rb,
                          float* __restrict__ Y)
{
  int idx = blockIdx.x * 256 + threadIdx.x;
  if (idx >= 16 * 25600) return;
  int b = idx / 25600, pix = idx - b * 25600;
  const float N = 32.f * 25600.f;
  float mean[2], rstd[2];
  #pragma unroll
  for (int g = 0; g < 2; ++g) {
    float s = st[(b * 2 + g) * 2], q = st[(b * 2 + g) * 2 + 1];
    float m = s / N;
    mean[g] = m; rstd[g] = rsqrtf(q / N - m * m + 1e-5f);
  }
  float a0 = rb[0], a1 = rb[1], a2 = rb[2];
  const float* dp = D + (size_t)(b * 64) * 25600 + pix;
  #pragma unroll 4
  for (int c = 0; c < 64; ++c) {
    float x = dp[(size_t)c * 25600];
    float t = (x - mean[c >> 5]) * rstd[c >> 5] * gw[c] + gb[c];
    float v = silu_f(t);
    a0 = fmaf(v, rw[c], a0);
    a1 = fmaf(v, rw[64 + c], a1);
    a2 = fmaf(v, rw[128 + c], a2);
  }
  Y[(size_t)(b * 3 + 0) * 25600 + pix] = a0;
  Y[(size_t)(b * 3 + 1) * 25600 + pix] = a1;
  Y[(size_t)(b * 3 + 2) * 25600 + pix] = a2;
}

// ---- feamap: argx = conv(Y, fw, stride 4)/16, first 3 channels ------------
__global__ void feamap_k(const float* __restrict__ Y, const float* __restrict__ fw,
                         float* __restrict__ argx)
{
  int idx = blockIdx.x * 256 + threadIdx.x;
  if (idx >= 16 * 3 * 1600) return;
  int b  = idx / (3 * 1600);
  int o  = (idx / 1600) % 3;
  int ij = idx % 1600;
  int i = ij / 40, j = ij - i * 40;
  float s = 0.f;
  #pragma unroll
  for (int c = 0; c < 3; ++c)
    #pragma unroll
    for (int u = 0; u < 4; ++u)
      #pragma unroll
      for (int v = 0; v < 4; ++v)
        s += Y[((size_t)(b * 3 + c) * 160 + (4 * i + u)) * 160 + (4 * j + v)]
             * fw[((o * 3 + c) * 4 + u) * 4 + v];
  argx[idx] = s * (1.f / 16.f);
}

__global__ void nz_k(const float* __restrict__ attn, float* __restrict__ nzinv) {
  int idx = blockIdx.x * 256 + threadIdx.x;
  if (idx >= 16 * 3 * 256) return;
  const float* p = attn + (size_t)idx * 16;
  int c = 0;
  #pragma unroll
  for (int k = 0; k < 16; ++k) c += (p[k] != 0.f);
  nzinv[idx] = 1.f / ((float)c + 1e-5f);
}

__global__ void final_k(const float* __restrict__ Y, const float* __restrict__ attn,
                        const float* __restrict__ nzinv, const float* __restrict__ argx,
                        float* __restrict__ out)
{
  int idx = blockIdx.x * 256 + threadIdx.x;
  if (idx >= 16 * 3 * 25600) return;
  int bc  = idx / 25600;
  int pix = idx - bc * 25600;
  int y = pix / 160, x = pix - y * 160;
  int l  = (y / 10) * 16 + (x / 10);
  int pi = y % 10,  pj = x % 10;
  const float* ar = attn + ((size_t)bc * 256 + l) * 16;
  const float* ax = argx + (size_t)bc * 1600;
  float inv = nzinv[bc * 256 + l];
  float corr = 0.f;
  #pragma unroll
  for (int k = 0; k < 16; ++k)
    corr += ar[k] * ax[((k >> 2) * 10 + pi) * 40 + ((k & 3) * 10 + pj)];
  float yv = Y[idx];
  out[idx] = yv * (1.f + corr * inv);
}

// ---------------------------------------------------------------------------
extern "C" void kernel_launch(void* const* d_in, const int* in_sizes, int n_in,
                              void* d_out, int out_size, void* d_ws, size_t ws_size,
                              hipStream_t stream)
{
  const float* attn = (const float*)d_in[0];
  const float* hid  = (const float*)d_in[1];
  const float* enc1 = (const float*)d_in[2];
  const float* d0w  = (const float*)d_in[3];
  const float* d0b  = (const float*)d_in[4];
  const float* d0gw = (const float*)d_in[5];
  const float* d0gb = (const float*)d_in[6];
  const float* d1w  = (const float*)d_in[7];
  const float* d1b  = (const float*)d_in[8];
  const float* d1gw = (const float*)d_in[9];
  const float* d1gb = (const float*)d_in[10];
  const float* d2w  = (const float*)d_in[11];
  const float* d2b  = (const float*)d_in[12];
  const float* d2gw = (const float*)d_in[13];
  const float* d2gb = (const float*)d_in[14];
  const float* d3w  = (const float*)d_in[15];
  const float* d3b  = (const float*)d_in[16];
  const float* d3gw = (const float*)d_in[17];
  const float* d3gb = (const float*)d_in[18];
  const float* rw   = (const float*)d_in[19];
  const float* rb   = (const float*)d_in[20];
  const float* fw   = (const float*)d_in[21];

  float* ws = (float*)d_ws;
  size_t o = 0;
  float* bufA  = ws + o; o += (size_t)16 * 64 * 80 * 80;       // A / Bb / Y+argx+nzv
  float* bufAp = ws + o; o += (size_t)16 * 82 * 82 * 64 / 2;   // Ap / Bp  (bf16)
  float* bufC  = ws + o; o += (size_t)16 * 64 * 160 * 160;     // Cb / Db
  float* bufCp = ws + o; o += (size_t)16 * 162 * 162 * 64 / 2; // Cp (bf16)
  float* hidPf = ws + o; o += (size_t)16 * 42 * 42 * 64 / 2;   // hidP (bf16)
  float* st    = ws + o; o += 256;
  float* w0f   = ws + o; o += (size_t)72 * 256 * 8 / 2;
  float* w1f   = ws + o; o += (size_t)72 * 64 * 8 / 2;
  float* w2f   = ws + o; o += (size_t)72 * 256 * 8 / 2;
  float* w3f   = ws + o; o += (size_t)72 * 64 * 8 / 2;

  float*  A    = bufA;
  float*  Bb   = bufA;
  ushort* Ap   = (ushort*)bufAp;
  ushort* Bp   = (ushort*)bufAp;
  float*  Cb   = bufC;
  float*  Db   = bufC;
  ushort* Cp   = (ushort*)bufCp;
  ushort* hidP = (ushort*)hidPf;
  float*  Y    = bufA;
  float*  argx = bufA + (size_t)16 * 3 * 25600;
  float*  nzv  = argx + (size_t)16 * 3 * 1600;
  ushort* w0   = (ushort*)w0f;
  ushort* w1   = (ushort*)w1f;
  ushort* w2   = (ushort*)w2f;
  ushort* w3   = (ushort*)w3f;

  zero_k<<<1, 256, 0, stream>>>(st, 256);

  repackw_k<256><<<(256 * 576 + 255) / 256, 256, 0, stream>>>(d0w, w0);
  repackw_k<64><<<(64 * 576 + 255) / 256, 256, 0, stream>>>(d1w, w1);
  repackw_k<256><<<(256 * 576 + 255) / 256, 256, 0, stream>>>(d2w, w2);
  repackw_k<64><<<(64 * 576 + 255) / 256, 256, 0, stream>>>(d3w, w3);

  // borders (zeroed every call; act kernels write interiors only)
  border_k<42, 42><<<(16 * 42 * 42 + 255) / 256, 256, 0, stream>>>(hidP);
  border_k<82, 82><<<(16 * 82 * 82 + 255) / 256, 256, 0, stream>>>(Ap);
  border_k<162, 162><<<(16 * 162 * 162 + 255) / 256, 256, 0, stream>>>(Cp);

  // pad hid -> hidP (NHWC bf16)
  act_k<1600, 40, 0><<<16 * 7, 256, 0, stream>>>(hid, nullptr, nullptr, nullptr,
                                                 nullptr, hidP);

  // stage 0: conv(hidP)+PS -> A, stats st+0   (40x40, OC=256, ragged NG=3)
  convm_k<40, 40, 4, 40, 3, 256, true>
    <<<dim3(10, 16 * 4), 256, 0, stream>>>((const uint4*)hidP, w0, d0b, A, st + 0);

  // act1 -> Ap
  act_k<6400, 80, 1><<<16 * 25, 256, 0, stream>>>(A, st + 0, d0gw, d0gb,
                                                  nullptr, Ap);
  // stage 1: conv(Ap) -> Bb, stats st+64
  convm_k<80, 80, 8, 16, 1, 64, false>
    <<<dim3(50, 16), 256, 0, stream>>>((const uint4*)Ap, w1, d1b, Bb, st + 64);

  // act2 -> Bp
  act_k<6400, 80, 1><<<16 * 25, 256, 0, stream>>>(Bb, st + 64, d1gw, d1gb,
                                                  nullptr, Bp);
  // stage 2: conv(Bp)+PS -> Cb, stats st+128
  convm_k<80, 80, 8, 16, 1, 256, true>
    <<<dim3(50, 16 * 4), 256, 0, stream>>>((const uint4*)Bp, w2, d2b, Cb, st + 128);

  // act3 (+enc1) -> Cp
  act_k<25600, 160, 2><<<16 * 100, 256, 0, stream>>>(Cb, st + 128, d2gw, d2gb,
                                                     enc1, Cp);
  // stage 3: conv(Cp) -> Db, stats st+192
  convm_k<160, 160, 8, 16, 1, 64, false>
    <<<dim3(200, 16), 256, 0, stream>>>((const uint4*)Cp, w3, d3b, Db, st + 192);

  // readout -> Y
  readout_k<<<(16 * 25600 + 255) / 256, 256, 0, stream>>>(Db, st + 192,
      d3gw, d3gb, rw, rb, Y);

  feamap_k<<<(16 * 3 * 1600 + 255) / 256, 256, 0, stream>>>(Y, fw, argx);
  nz_k<<<(16 * 3 * 256 + 255) / 256, 256, 0, stream>>>(attn, nzv);
  final_k<<<(16 * 3 * 25600 + 255) / 256, 256, 0, stream>>>(Y, attn, nzv, argx,
      (float*)d_out);
}